// Round 2
// baseline (412.844 us; speedup 1.0000x reference)
//
#include <hip/hip_runtime.h>

// CavityModel forward (all f32): gaussian blur -> 3x(conv3d+maxpool+BN(batch
// stats)+leaky) -> dense 64->128 (+BN+leaky) -> 128->100 (+leaky) -> 100->20.

#define G2 324
#define G3 5832
#define NT 6
#define BATCH 256
#define APE 100
#define EPS 1e-5f

__device__ __forceinline__ float leaky(float x) { return x >= 0.0f ? x : 0.01f * x; }

// ---------- K1: fused gaussian blur (separable, 9^3 window) + conv1 + pool + bn1 stats
// one block per env; field [6][18^3] lives in LDS end-to-end (no HBM round trip).
__global__ __launch_bounds__(512) void k_blur_conv1(const float* __restrict__ pos,
        const int* __restrict__ types,
        const float* __restrict__ w, const float* __restrict__ bias,
        float* __restrict__ a1, float* __restrict__ stO) {
    __shared__ float fld[NT * G3];   // 139968 B
    __shared__ float uni[2700];      // phase A: ew[atom][axis][9]; phase B: ws1[2592]
    __shared__ short i0a[APE * 3];   // per (atom,axis) window start
    __shared__ int   tt[APE];
    __shared__ float bs[16], s_sum[16], s_ssq[16];
    const int b = blockIdx.x, tid = threadIdx.x;

    for (int i = tid; i < NT * G3; i += 512) fld[i] = 0.0f;
    if (tid < 300) {
        const int la = tid / 3, ax = tid % 3;
        const float p = pos[(b * APE + la) * 3 + ax];
        int i0 = (int)ceilf(p + 4.0f);
        i0 = max(0, min(9, i0));
        i0a[tid] = (short)i0;
        float e[18], s = 0.0f;
        #pragma unroll
        for (int g = 0; g < 18; ++g) {
            float d = (float)g - 8.5f - p;
            e[g] = __expf(d * d * (-1.0f / 0.72f));
            s += e[g];
        }
        const float inv = 1.0f / s;   // per-axis normalizer; product over axes = full
        #pragma unroll
        for (int q = 0; q < 9; ++q) uni[la * 27 + ax * 9 + q] = e[i0 + q] * inv;
    }
    if (tid < APE) tt[tid] = types[b * APE + tid];
    __syncthreads();

    for (int la = 0; la < APE; ++la) {
        const int t = tt[la];
        const float* ew = &uni[la * 27];
        const int i0x = i0a[la * 3], i0y = i0a[la * 3 + 1], i0z = i0a[la * 3 + 2];
        for (int idx = tid; idx < 729; idx += 512) {
            const int di = idx / 81, r = idx % 81, dj = r / 9, dk = r % 9;
            atomicAdd(&fld[t * G3 + (i0x + di) * G2 + (i0y + dj) * 18 + (i0z + dk)],
                      ew[di] * ew[9 + dj] * ew[18 + dk]);
        }
    }
    __syncthreads();

    // phase B: conv1 (6->16, pad1) + maxpool2 -> [16,9^3] (+bias) + batch stats
    for (int i = tid; i < 2592; i += 512) uni[i] = w[i];
    if (tid < 16) { bs[tid] = bias[tid]; s_sum[tid] = 0.0f; s_ssq[tid] = 0.0f; }
    __syncthreads();

    for (int idx = tid; idx < 648; idx += 512) {
        const int c2 = idx / 81, XY = idx % 81, X = XY / 9, Y = XY % 9;
        const int c0 = 2 * c2, c1 = c0 + 1;
        float pool0[9], pool1[9];
        #pragma unroll
        for (int Z = 0; Z < 9; ++Z) { pool0[Z] = -1e30f; pool1[Z] = -1e30f; }
        for (int oxi = 0; oxi < 2; ++oxi) {
            const int ox = 2 * X + oxi;
            for (int oyi = 0; oyi < 2; ++oyi) {
                const int oy = 2 * Y + oyi;
                float acc0[18], acc1[18];
                #pragma unroll
                for (int z = 0; z < 18; ++z) { acc0[z] = 0.0f; acc1[z] = 0.0f; }
                for (int ic = 0; ic < 6; ++ic) {
                    #pragma unroll
                    for (int dx = 0; dx < 3; ++dx) {
                        const int ix = ox + dx - 1;
                        if (ix < 0 || ix > 17) continue;
                        #pragma unroll
                        for (int dy = 0; dy < 3; ++dy) {
                            const int iy = oy + dy - 1;
                            if (iy < 0 || iy > 17) continue;
                            const float* rp = &fld[ic * G3 + ix * G2 + iy * 18];
                            float row[18];
                            #pragma unroll
                            for (int z = 0; z < 18; ++z) row[z] = rp[z];
                            const int wb0 = (c0 * 6 + ic) * 27 + dx * 9 + dy * 3;
                            const int wb1 = (c1 * 6 + ic) * 27 + dx * 9 + dy * 3;
                            #pragma unroll
                            for (int dz = 0; dz < 3; ++dz) {
                                const float w0 = uni[wb0 + dz];
                                const float w1v = uni[wb1 + dz];
                                #pragma unroll
                                for (int z = 0; z < 18; ++z) {
                                    const int iz = z + dz - 1;
                                    if (iz >= 0 && iz < 18) {
                                        acc0[z] += w0 * row[iz];
                                        acc1[z] += w1v * row[iz];
                                    }
                                }
                            }
                        }
                    }
                }
                #pragma unroll
                for (int Z = 0; Z < 9; ++Z) {
                    pool0[Z] = fmaxf(pool0[Z], fmaxf(acc0[2 * Z], acc0[2 * Z + 1]));
                    pool1[Z] = fmaxf(pool1[Z], fmaxf(acc1[2 * Z], acc1[2 * Z + 1]));
                }
            }
        }
        const float b0 = bs[c0], b1 = bs[c1];
        float s0 = 0, q0 = 0, s1 = 0, q1 = 0;
        float* o0 = &a1[((size_t)b * 16 + c0) * 729 + X * 81 + Y * 9];
        float* o1 = &a1[((size_t)b * 16 + c1) * 729 + X * 81 + Y * 9];
        #pragma unroll
        for (int Z = 0; Z < 9; ++Z) {
            float v0 = pool0[Z] + b0, v1 = pool1[Z] + b1;
            o0[Z] = v0; o1[Z] = v1;
            s0 += v0; q0 += v0 * v0; s1 += v1; q1 += v1 * v1;
        }
        atomicAdd(&s_sum[c0], s0); atomicAdd(&s_ssq[c0], q0);
        atomicAdd(&s_sum[c1], s1); atomicAdd(&s_ssq[c1], q1);
    }
    __syncthreads();
    if (tid < 16) { atomicAdd(&stO[tid], s_sum[tid]); atomicAdd(&stO[16 + tid], s_ssq[tid]); }
}

// ---------- K2: bn1+leaky -> conv2 (16->32, pad0, 9^3->7^3) + pool -> [32,3^3] + bn2 stats
__global__ __launch_bounds__(512) void k_conv2(const float* __restrict__ a1,
        const float* __restrict__ w, const float* __restrict__ bias,
        const float* __restrict__ bng, const float* __restrict__ bnb,
        const float* __restrict__ stI, float* __restrict__ a2,
        float* __restrict__ stO) {
    __shared__ float xin[16 * 729];   // 46656 B
    __shared__ float ws2[13824];      // 55296 B
    __shared__ float ps[576 * 6];     // 13824 B
    __shared__ float sc[16], sh[16];
    __shared__ float s_sum[32], s_ssq[32];
    const int b = blockIdx.x, tid = threadIdx.x;
    if (tid < 16) {
        const float cnt = 256.0f * 729.0f;
        float m = stI[tid] / cnt;
        float v = stI[16 + tid] / cnt - m * m;
        float s = bng[tid] * rsqrtf(fmaxf(v, 0.0f) + EPS);
        sc[tid] = s; sh[tid] = bnb[tid] - m * s;
    }
    if (tid < 32) { s_sum[tid] = 0.0f; s_ssq[tid] = 0.0f; }
    __syncthreads();
    const float* src = a1 + (size_t)b * 16 * 729;
    for (int i = tid; i < 16 * 729; i += 512) {
        int c = i / 729;
        xin[i] = leaky(src[i] * sc[c] + sh[c]);
    }
    for (int i = tid; i < 13824; i += 512) ws2[i] = w[i];
    __syncthreads();
    for (int idx = tid; idx < 576; idx += 512) {
        const int c2 = idx / 36, r = idx % 36, X = r / 12, r2 = r % 12;
        const int Y = r2 / 4, o = r2 % 4, oxi = o >> 1, oyi = o & 1;
        const int ox = 2 * X + oxi, oy = 2 * Y + oyi;   // 0..5
        const int c0 = c2 * 2, c1 = c0 + 1;
        float acc0[6], acc1[6];
        #pragma unroll
        for (int z = 0; z < 6; ++z) { acc0[z] = 0.0f; acc1[z] = 0.0f; }
        for (int ic = 0; ic < 16; ++ic) {
            #pragma unroll
            for (int dx = 0; dx < 3; ++dx) {
                const int ix = ox + dx;
                #pragma unroll
                for (int dy = 0; dy < 3; ++dy) {
                    const int iy = oy + dy;
                    const float* rp = &xin[ic * 729 + ix * 81 + iy * 9];
                    float row[9];
                    #pragma unroll
                    for (int z = 0; z < 9; ++z) row[z] = rp[z];
                    const int wb0 = (c0 * 16 + ic) * 27 + dx * 9 + dy * 3;
                    const int wb1 = (c1 * 16 + ic) * 27 + dx * 9 + dy * 3;
                    #pragma unroll
                    for (int dz = 0; dz < 3; ++dz) {
                        const float w0 = ws2[wb0 + dz];
                        const float w1v = ws2[wb1 + dz];
                        #pragma unroll
                        for (int z = 0; z < 6; ++z) {
                            acc0[z] += w0 * row[z + dz];
                            acc1[z] += w1v * row[z + dz];
                        }
                    }
                }
            }
        }
        #pragma unroll
        for (int Z = 0; Z < 3; ++Z) {
            ps[idx * 6 + Z]     = fmaxf(acc0[2 * Z], acc0[2 * Z + 1]);
            ps[idx * 6 + 3 + Z] = fmaxf(acc1[2 * Z], acc1[2 * Z + 1]);
        }
    }
    __syncthreads();
    for (int i = tid; i < 864; i += 512) {
        const int c = i / 27, r = i % 27;
        const int X = r / 9, Y = (r / 3) % 3, Z = r % 3;
        const int c2 = c >> 1, half = c & 1;
        const int base = (c2 * 36 + X * 12 + Y * 4) * 6 + half * 3 + Z;
        float m = fmaxf(fmaxf(ps[base], ps[base + 6]),
                        fmaxf(ps[base + 12], ps[base + 18]));
        float v = m + bias[c];
        a2[((size_t)b * 32 + c) * 27 + r] = v;
        atomicAdd(&s_sum[c], v); atomicAdd(&s_ssq[c], v * v);
    }
    __syncthreads();
    if (tid < 32) { atomicAdd(&stO[tid], s_sum[tid]); atomicAdd(&stO[32 + tid], s_ssq[tid]); }
}

// ---------- K3: bn2+leaky -> conv3 (32->64, pad1, 3^3) + pool -> [64] + bn3 stats
__global__ __launch_bounds__(256) void k_conv3(const float* __restrict__ a2,
        const float* __restrict__ w, const float* __restrict__ bias,
        const float* __restrict__ bng, const float* __restrict__ bnb,
        const float* __restrict__ stI, float* __restrict__ a3,
        float* __restrict__ stO) {
    __shared__ float x[864];
    __shared__ float pacc[256 * 8];
    __shared__ float sc[32], sh[32];
    const int b = blockIdx.x, tid = threadIdx.x;
    if (tid < 32) {
        const float cnt = 256.0f * 27.0f;
        float m = stI[tid] / cnt;
        float v = stI[32 + tid] / cnt - m * m;
        float s = bng[tid] * rsqrtf(fmaxf(v, 0.0f) + EPS);
        sc[tid] = s; sh[tid] = bnb[tid] - m * s;
    }
    __syncthreads();
    for (int i = tid; i < 864; i += 256) {
        int c = i / 27;
        x[i] = leaky(a2[(size_t)b * 864 + i] * sc[c] + sh[c]);
    }
    __syncthreads();
    // thread = (out channel c, ic-quadrant q); weights straight from global (L2-resident)
    const int c = tid & 63, q = tid >> 6;
    float acc[8];
    #pragma unroll
    for (int p = 0; p < 8; ++p) acc[p] = 0.0f;
    for (int ic = q * 8; ic < q * 8 + 8; ++ic) {
        const float* wr = w + ((size_t)c * 32 + ic) * 27;
        #pragma unroll
        for (int d = 0; d < 27; ++d) {
            const int dx = d / 9, dy = (d / 3) % 3, dz = d % 3;
            const float wv = wr[d];
            #pragma unroll
            for (int p = 0; p < 8; ++p) {
                const int px = p >> 2, py = (p >> 1) & 1, pz = p & 1;
                const int ix = px + dx - 1, iy = py + dy - 1, iz = pz + dz - 1;
                if (ix >= 0 && iy >= 0 && iz >= 0)   // upper bounds always <= 2
                    acc[p] += wv * x[ic * 27 + ix * 9 + iy * 3 + iz];
            }
        }
    }
    #pragma unroll
    for (int p = 0; p < 8; ++p) pacc[tid * 8 + p] = acc[p];
    __syncthreads();
    if (q == 0) {
        float m = -1e30f;
        #pragma unroll
        for (int p = 0; p < 8; ++p) {
            float v = pacc[c * 8 + p] + pacc[(64 + c) * 8 + p]
                    + pacc[(128 + c) * 8 + p] + pacc[(192 + c) * 8 + p];
            m = fmaxf(m, v);
        }
        float v = m + bias[c];
        a3[(size_t)b * 64 + c] = v;
        atomicAdd(&stO[c], v); atomicAdd(&stO[64 + c], v * v);
    }
}

// ---------- K4: bn3+leaky -> dense 64->128 (pre-bn4) + bn4 stats
__global__ __launch_bounds__(128) void k_dense1(const float* __restrict__ a3,
        const float* __restrict__ bng, const float* __restrict__ bnb,
        const float* __restrict__ stI,
        const float* __restrict__ w1, const float* __restrict__ b1,
        float* __restrict__ h1, float* __restrict__ stO) {
    __shared__ float x[64];
    const int b = blockIdx.x, tid = threadIdx.x;
    if (tid < 64) {
        float m = stI[tid] / 256.0f;
        float v = stI[64 + tid] / 256.0f - m * m;
        float s = bng[tid] * rsqrtf(fmaxf(v, 0.0f) + EPS);
        x[tid] = leaky(a3[(size_t)b * 64 + tid] * s + (bnb[tid] - m * s));
    }
    __syncthreads();
    const float* wr = w1 + tid * 64;
    float acc = b1[tid];
    #pragma unroll
    for (int i = 0; i < 64; ++i) acc += x[i] * wr[i];
    h1[(size_t)b * 128 + tid] = acc;
    atomicAdd(&stO[tid], acc); atomicAdd(&stO[128 + tid], acc * acc);
}

// ---------- K5: bn4+leaky -> 128->100 (+leaky) -> 100->20 -> out (f32)
__global__ __launch_bounds__(128) void k_dense2(const float* __restrict__ h1,
        const float* __restrict__ bng, const float* __restrict__ bnb,
        const float* __restrict__ stI,
        const float* __restrict__ w2, const float* __restrict__ bias2,
        const float* __restrict__ w3, const float* __restrict__ bias3,
        float* __restrict__ out) {
    __shared__ float x[128];
    __shared__ float y[100];
    const int b = blockIdx.x, tid = threadIdx.x;
    {
        float m = stI[tid] / 256.0f;
        float v = stI[128 + tid] / 256.0f - m * m;
        float s = bng[tid] * rsqrtf(fmaxf(v, 0.0f) + EPS);
        x[tid] = leaky(h1[(size_t)b * 128 + tid] * s + (bnb[tid] - m * s));
    }
    __syncthreads();
    if (tid < 100) {
        const float* wr = w2 + tid * 128;
        float acc = bias2[tid];
        #pragma unroll
        for (int i = 0; i < 128; ++i) acc += x[i] * wr[i];
        y[tid] = leaky(acc);
    }
    __syncthreads();
    if (tid < 20) {
        const float* wr = w3 + tid * 100;
        float acc = bias3[tid];
        #pragma unroll
        for (int i = 0; i < 100; ++i) acc += y[i] * wr[i];
        out[(size_t)b * 20 + tid] = acc;
    }
}

extern "C" void kernel_launch(void* const* d_in, const int* in_sizes, int n_in,
                              void* d_out, int out_size, void* d_ws, size_t ws_size,
                              hipStream_t stream) {
    (void)in_sizes; (void)n_in; (void)out_size; (void)ws_size;
    const float* pos  = (const float*)d_in[0];
    const float* c1w  = (const float*)d_in[1];
    const float* c1b  = (const float*)d_in[2];
    const float* bn1g = (const float*)d_in[3];
    const float* bn1b = (const float*)d_in[4];
    const float* c2w  = (const float*)d_in[5];
    const float* c2b  = (const float*)d_in[6];
    const float* bn2g = (const float*)d_in[7];
    const float* bn2b = (const float*)d_in[8];
    const float* c3w  = (const float*)d_in[9];
    const float* c3b  = (const float*)d_in[10];
    const float* bn3g = (const float*)d_in[11];
    const float* bn3b = (const float*)d_in[12];
    const float* d1w  = (const float*)d_in[13];
    const float* d1b  = (const float*)d_in[14];
    const float* bn4g = (const float*)d_in[15];
    const float* bn4b = (const float*)d_in[16];
    const float* d2w  = (const float*)d_in[17];
    const float* d2b  = (const float*)d_in[18];
    const float* d3w  = (const float*)d_in[19];
    const float* d3b  = (const float*)d_in[20];
    const int* types  = (const int*)d_in[22];   // d_in[21]=batch_ids implied by layout

    float* ws = (float*)d_ws;
    float* st = ws;                         // 480 f (bn stats; small arrays first)
    float* a3 = ws + 512;                   // 16,384 f
    float* h1 = a3 + 16384;                 // 32,768 f
    float* a2 = h1 + 32768;                 // 221,184 f
    float* a1 = a2 + 221184;                // 2,985,984 f   (total ~13 MB)

    hipMemsetAsync(st, 0, 480 * sizeof(float), stream);
    k_blur_conv1<<<BATCH, 512, 0, stream>>>(pos, types, c1w, c1b, a1, st);
    k_conv2     <<<BATCH, 512, 0, stream>>>(a1, c2w, c2b, bn1g, bn1b, st, a2, st + 32);
    k_conv3     <<<BATCH, 256, 0, stream>>>(a2, c3w, c3b, bn2g, bn2b, st + 32, a3, st + 96);
    k_dense1    <<<BATCH, 128, 0, stream>>>(a3, bn3g, bn3b, st + 96, d1w, d1b, h1, st + 224);
    k_dense2    <<<BATCH, 128, 0, stream>>>(h1, bn4g, bn4b, st + 224, d2w, d2b, d3w, d3b,
                                            (float*)d_out);
}

// Round 3
// 314.050 us; speedup vs baseline: 1.3146x; 1.3146x over previous
//
#include <hip/hip_runtime.h>

// CavityModel forward (all f32): gaussian blur -> 3x(conv3d+maxpool+BN(batch
// stats)+leaky) -> dense 64->128 (+BN+leaky) -> 128->100 (+leaky) -> 100->20.

#define G2 324
#define G3 5832
#define NT 6
#define BATCH 256
#define APE 100
#define EPS 1e-5f

__device__ __forceinline__ float leaky(float x) { return x >= 0.0f ? x : 0.01f * x; }

// ---------- K1: fused gaussian blur (separable, 9^3 window) + conv1 + pool + bn1 stats
// one block per env; field [6][18^3] lives in LDS end-to-end (no HBM round trip).
// conv phase: item = (c4, X, Y, oxi, oyi), 4-channel register blocking, 18-z strip,
// 2x2 pool window combined in-register via shfl_xor over the lane quad.
__global__ __launch_bounds__(512) void k_blur_conv1(const float* __restrict__ pos,
        const int* __restrict__ types,
        const float* __restrict__ w, const float* __restrict__ bias,
        float* __restrict__ a1, float* __restrict__ stO) {
    __shared__ float fld[NT * G3];   // 139968 B
    __shared__ float uni[2700];      // phase A: ew[atom][axis][9]; phase B: ws1[2592]
    __shared__ short i0a[APE * 3];   // per (atom,axis) window start
    __shared__ int   tt[APE];
    __shared__ float bs[16], s_sum[16], s_ssq[16];
    const int b = blockIdx.x, tid = threadIdx.x;

    for (int i = tid; i < NT * G3; i += 512) fld[i] = 0.0f;
    if (tid < 300) {
        const int la = tid / 3, ax = tid % 3;
        const float p = pos[(b * APE + la) * 3 + ax];
        int i0 = (int)ceilf(p + 4.0f);
        i0 = max(0, min(9, i0));
        i0a[tid] = (short)i0;
        float e[18], s = 0.0f;
        #pragma unroll
        for (int g = 0; g < 18; ++g) {
            float d = (float)g - 8.5f - p;
            e[g] = __expf(d * d * (-1.0f / 0.72f));
            s += e[g];
        }
        const float inv = 1.0f / s;   // per-axis normalizer; product over axes = full
        #pragma unroll
        for (int q = 0; q < 9; ++q) uni[la * 27 + ax * 9 + q] = e[i0 + q] * inv;
    }
    if (tid < APE) tt[tid] = types[b * APE + tid];
    __syncthreads();

    for (int la = 0; la < APE; ++la) {
        const int t = tt[la];
        const float* ew = &uni[la * 27];
        const int i0x = i0a[la * 3], i0y = i0a[la * 3 + 1], i0z = i0a[la * 3 + 2];
        for (int idx = tid; idx < 729; idx += 512) {
            const int di = idx / 81, r = idx % 81, dj = r / 9, dk = r % 9;
            atomicAdd(&fld[t * G3 + (i0x + di) * G2 + (i0y + dj) * 18 + (i0z + dk)],
                      ew[di] * ew[9 + dj] * ew[18 + dk]);
        }
    }
    __syncthreads();

    // phase B: conv1 (6->16, pad1) + maxpool2 -> [16,9^3] (+bias) + batch stats
    for (int i = tid; i < 2592; i += 512) uni[i] = w[i];
    if (tid < 16) { bs[tid] = bias[tid]; s_sum[tid] = 0.0f; s_ssq[tid] = 0.0f; }
    __syncthreads();

    // items: oyi = idx&1, oxi = (idx>>1)&1, Y, X, c4  (1296 total, 3 passes)
    for (int base = 0; base < 1296; base += 512) {
        const int idx = base + tid;
        if (idx < 1296) {
            const int oyi = idx & 1, oxi = (idx >> 1) & 1, rest = idx >> 2;
            const int Y = rest % 9, X = (rest / 9) % 9, c4 = rest / 81;  // 0..3
            const int ox = 2 * X + oxi, oy = 2 * Y + oyi;
            float acc[4][18];
            #pragma unroll
            for (int cc = 0; cc < 4; ++cc)
                #pragma unroll
                for (int z = 0; z < 18; ++z) acc[cc][z] = 0.0f;
            for (int ic = 0; ic < 6; ++ic) {
                #pragma unroll
                for (int dx = 0; dx < 3; ++dx) {
                    const int ix = ox + dx - 1;
                    if (ix < 0 || ix > 17) continue;
                    #pragma unroll
                    for (int dy = 0; dy < 3; ++dy) {
                        const int iy = oy + dy - 1;
                        if (iy < 0 || iy > 17) continue;
                        const float2* rp2 =
                            (const float2*)&fld[ic * G3 + ix * G2 + iy * 18];
                        float row[18];
                        #pragma unroll
                        for (int j = 0; j < 9; ++j) {
                            const float2 t2 = rp2[j];
                            row[2 * j] = t2.x; row[2 * j + 1] = t2.y;
                        }
                        float wv[4][3];
                        #pragma unroll
                        for (int cc = 0; cc < 4; ++cc)
                            #pragma unroll
                            for (int dz = 0; dz < 3; ++dz)
                                wv[cc][dz] = uni[((c4 * 4 + cc) * 6 + ic) * 27
                                                 + dx * 9 + dy * 3 + dz];
                        #pragma unroll
                        for (int dz = 0; dz < 3; ++dz) {
                            #pragma unroll
                            for (int z = 0; z < 18; ++z) {
                                const int iz = z + dz - 1;      // compile-time bounds
                                if (iz >= 0 && iz < 18) {
                                    #pragma unroll
                                    for (int cc = 0; cc < 4; ++cc)
                                        acc[cc][z] += wv[cc][dz] * row[iz];
                                }
                            }
                        }
                    }
                }
            }
            // z-pool then 2x2 xy-pool across the lane quad (bits 0,1 = oyi,oxi)
            float pl[4][9];
            #pragma unroll
            for (int cc = 0; cc < 4; ++cc)
                #pragma unroll
                for (int Z = 0; Z < 9; ++Z) {
                    float v = fmaxf(acc[cc][2 * Z], acc[cc][2 * Z + 1]);
                    v = fmaxf(v, __shfl_xor(v, 1));
                    v = fmaxf(v, __shfl_xor(v, 2));
                    pl[cc][Z] = v;
                }
            if (oyi == 0 && oxi == 0) {
                #pragma unroll
                for (int cc = 0; cc < 4; ++cc) {
                    const int c = c4 * 4 + cc;
                    const float bb = bs[c];
                    float s0 = 0.0f, q0 = 0.0f;
                    float* o = &a1[((size_t)b * 16 + c) * 729 + X * 81 + Y * 9];
                    #pragma unroll
                    for (int Z = 0; Z < 9; ++Z) {
                        const float v = pl[cc][Z] + bb;
                        o[Z] = v;
                        s0 += v; q0 += v * v;
                    }
                    atomicAdd(&s_sum[c], s0); atomicAdd(&s_ssq[c], q0);
                }
            }
        }
    }
    __syncthreads();
    if (tid < 16) { atomicAdd(&stO[tid], s_sum[tid]); atomicAdd(&stO[16 + tid], s_ssq[tid]); }
}

// ---------- K2: bn1+leaky -> conv2 (16->32, pad0, 9^3->7^3) + pool -> [32,3^3] + bn2 stats
__global__ __launch_bounds__(512) void k_conv2(const float* __restrict__ a1,
        const float* __restrict__ w, const float* __restrict__ bias,
        const float* __restrict__ bng, const float* __restrict__ bnb,
        const float* __restrict__ stI, float* __restrict__ a2,
        float* __restrict__ stO) {
    __shared__ float xin[16 * 729];   // 46656 B
    __shared__ float ws2[13824];      // 55296 B
    __shared__ float ps[576 * 6];     // 13824 B
    __shared__ float sc[16], sh[16];
    __shared__ float s_sum[32], s_ssq[32];
    const int b = blockIdx.x, tid = threadIdx.x;
    if (tid < 16) {
        const float cnt = 256.0f * 729.0f;
        float m = stI[tid] / cnt;
        float v = stI[16 + tid] / cnt - m * m;
        float s = bng[tid] * rsqrtf(fmaxf(v, 0.0f) + EPS);
        sc[tid] = s; sh[tid] = bnb[tid] - m * s;
    }
    if (tid < 32) { s_sum[tid] = 0.0f; s_ssq[tid] = 0.0f; }
    __syncthreads();
    const float* src = a1 + (size_t)b * 16 * 729;
    for (int i = tid; i < 16 * 729; i += 512) {
        int c = i / 729;
        xin[i] = leaky(src[i] * sc[c] + sh[c]);
    }
    for (int i = tid; i < 13824; i += 512) ws2[i] = w[i];
    __syncthreads();
    for (int idx = tid; idx < 576; idx += 512) {
        const int c2 = idx / 36, r = idx % 36, X = r / 12, r2 = r % 12;
        const int Y = r2 / 4, o = r2 % 4, oxi = o >> 1, oyi = o & 1;
        const int ox = 2 * X + oxi, oy = 2 * Y + oyi;   // 0..5
        const int c0 = c2 * 2, c1 = c0 + 1;
        float acc0[6], acc1[6];
        #pragma unroll
        for (int z = 0; z < 6; ++z) { acc0[z] = 0.0f; acc1[z] = 0.0f; }
        for (int ic = 0; ic < 16; ++ic) {
            #pragma unroll
            for (int dx = 0; dx < 3; ++dx) {
                const int ix = ox + dx;
                #pragma unroll
                for (int dy = 0; dy < 3; ++dy) {
                    const int iy = oy + dy;
                    const float* rp = &xin[ic * 729 + ix * 81 + iy * 9];
                    float row[9];
                    #pragma unroll
                    for (int z = 0; z < 9; ++z) row[z] = rp[z];
                    const int wb0 = (c0 * 16 + ic) * 27 + dx * 9 + dy * 3;
                    const int wb1 = (c1 * 16 + ic) * 27 + dx * 9 + dy * 3;
                    #pragma unroll
                    for (int dz = 0; dz < 3; ++dz) {
                        const float w0 = ws2[wb0 + dz];
                        const float w1v = ws2[wb1 + dz];
                        #pragma unroll
                        for (int z = 0; z < 6; ++z) {
                            acc0[z] += w0 * row[z + dz];
                            acc1[z] += w1v * row[z + dz];
                        }
                    }
                }
            }
        }
        #pragma unroll
        for (int Z = 0; Z < 3; ++Z) {
            ps[idx * 6 + Z]     = fmaxf(acc0[2 * Z], acc0[2 * Z + 1]);
            ps[idx * 6 + 3 + Z] = fmaxf(acc1[2 * Z], acc1[2 * Z + 1]);
        }
    }
    __syncthreads();
    for (int i = tid; i < 864; i += 512) {
        const int c = i / 27, r = i % 27;
        const int X = r / 9, Y = (r / 3) % 3, Z = r % 3;
        const int c2 = c >> 1, half = c & 1;
        const int base = (c2 * 36 + X * 12 + Y * 4) * 6 + half * 3 + Z;
        float m = fmaxf(fmaxf(ps[base], ps[base + 6]),
                        fmaxf(ps[base + 12], ps[base + 18]));
        float v = m + bias[c];
        a2[((size_t)b * 32 + c) * 27 + r] = v;
        atomicAdd(&s_sum[c], v); atomicAdd(&s_ssq[c], v * v);
    }
    __syncthreads();
    if (tid < 32) { atomicAdd(&stO[tid], s_sum[tid]); atomicAdd(&stO[32 + tid], s_ssq[tid]); }
}

// ---------- K3: bn2+leaky -> conv3 (32->64, pad1, 3^3) + pool -> [64] + bn3 stats
__global__ __launch_bounds__(256) void k_conv3(const float* __restrict__ a2,
        const float* __restrict__ w, const float* __restrict__ bias,
        const float* __restrict__ bng, const float* __restrict__ bnb,
        const float* __restrict__ stI, float* __restrict__ a3,
        float* __restrict__ stO) {
    __shared__ float x[864];
    __shared__ float pacc[256 * 8];
    __shared__ float sc[32], sh[32];
    const int b = blockIdx.x, tid = threadIdx.x;
    if (tid < 32) {
        const float cnt = 256.0f * 27.0f;
        float m = stI[tid] / cnt;
        float v = stI[32 + tid] / cnt - m * m;
        float s = bng[tid] * rsqrtf(fmaxf(v, 0.0f) + EPS);
        sc[tid] = s; sh[tid] = bnb[tid] - m * s;
    }
    __syncthreads();
    for (int i = tid; i < 864; i += 256) {
        int c = i / 27;
        x[i] = leaky(a2[(size_t)b * 864 + i] * sc[c] + sh[c]);
    }
    __syncthreads();
    // thread = (out channel c, ic-quadrant q); weights straight from global (L2-resident)
    const int c = tid & 63, q = tid >> 6;
    float acc[8];
    #pragma unroll
    for (int p = 0; p < 8; ++p) acc[p] = 0.0f;
    for (int ic = q * 8; ic < q * 8 + 8; ++ic) {
        const float* wr = w + ((size_t)c * 32 + ic) * 27;
        #pragma unroll
        for (int d = 0; d < 27; ++d) {
            const int dx = d / 9, dy = (d / 3) % 3, dz = d % 3;
            const float wv = wr[d];
            #pragma unroll
            for (int p = 0; p < 8; ++p) {
                const int px = p >> 2, py = (p >> 1) & 1, pz = p & 1;
                const int ix = px + dx - 1, iy = py + dy - 1, iz = pz + dz - 1;
                if (ix >= 0 && iy >= 0 && iz >= 0)   // upper bounds always <= 2
                    acc[p] += wv * x[ic * 27 + ix * 9 + iy * 3 + iz];
            }
        }
    }
    #pragma unroll
    for (int p = 0; p < 8; ++p) pacc[tid * 8 + p] = acc[p];
    __syncthreads();
    if (q == 0) {
        float m = -1e30f;
        #pragma unroll
        for (int p = 0; p < 8; ++p) {
            float v = pacc[c * 8 + p] + pacc[(64 + c) * 8 + p]
                    + pacc[(128 + c) * 8 + p] + pacc[(192 + c) * 8 + p];
            m = fmaxf(m, v);
        }
        float v = m + bias[c];
        a3[(size_t)b * 64 + c] = v;
        atomicAdd(&stO[c], v); atomicAdd(&stO[64 + c], v * v);
    }
}

// ---------- K4: bn3+leaky -> dense 64->128 (pre-bn4) + bn4 stats
__global__ __launch_bounds__(128) void k_dense1(const float* __restrict__ a3,
        const float* __restrict__ bng, const float* __restrict__ bnb,
        const float* __restrict__ stI,
        const float* __restrict__ w1, const float* __restrict__ b1,
        float* __restrict__ h1, float* __restrict__ stO) {
    __shared__ float x[64];
    const int b = blockIdx.x, tid = threadIdx.x;
    if (tid < 64) {
        float m = stI[tid] / 256.0f;
        float v = stI[64 + tid] / 256.0f - m * m;
        float s = bng[tid] * rsqrtf(fmaxf(v, 0.0f) + EPS);
        x[tid] = leaky(a3[(size_t)b * 64 + tid] * s + (bnb[tid] - m * s));
    }
    __syncthreads();
    const float* wr = w1 + tid * 64;
    float acc = b1[tid];
    #pragma unroll
    for (int i = 0; i < 64; ++i) acc += x[i] * wr[i];
    h1[(size_t)b * 128 + tid] = acc;
    atomicAdd(&stO[tid], acc); atomicAdd(&stO[128 + tid], acc * acc);
}

// ---------- K5: bn4+leaky -> 128->100 (+leaky) -> 100->20 -> out (f32)
__global__ __launch_bounds__(128) void k_dense2(const float* __restrict__ h1,
        const float* __restrict__ bng, const float* __restrict__ bnb,
        const float* __restrict__ stI,
        const float* __restrict__ w2, const float* __restrict__ bias2,
        const float* __restrict__ w3, const float* __restrict__ bias3,
        float* __restrict__ out) {
    __shared__ float x[128];
    __shared__ float y[100];
    const int b = blockIdx.x, tid = threadIdx.x;
    {
        float m = stI[tid] / 256.0f;
        float v = stI[128 + tid] / 256.0f - m * m;
        float s = bng[tid] * rsqrtf(fmaxf(v, 0.0f) + EPS);
        x[tid] = leaky(h1[(size_t)b * 128 + tid] * s + (bnb[tid] - m * s));
    }
    __syncthreads();
    if (tid < 100) {
        const float* wr = w2 + tid * 128;
        float acc = bias2[tid];
        #pragma unroll
        for (int i = 0; i < 128; ++i) acc += x[i] * wr[i];
        y[tid] = leaky(acc);
    }
    __syncthreads();
    if (tid < 20) {
        const float* wr = w3 + tid * 100;
        float acc = bias3[tid];
        #pragma unroll
        for (int i = 0; i < 100; ++i) acc += y[i] * wr[i];
        out[(size_t)b * 20 + tid] = acc;
    }
}

extern "C" void kernel_launch(void* const* d_in, const int* in_sizes, int n_in,
                              void* d_out, int out_size, void* d_ws, size_t ws_size,
                              hipStream_t stream) {
    (void)in_sizes; (void)n_in; (void)out_size; (void)ws_size;
    const float* pos  = (const float*)d_in[0];
    const float* c1w  = (const float*)d_in[1];
    const float* c1b  = (const float*)d_in[2];
    const float* bn1g = (const float*)d_in[3];
    const float* bn1b = (const float*)d_in[4];
    const float* c2w  = (const float*)d_in[5];
    const float* c2b  = (const float*)d_in[6];
    const float* bn2g = (const float*)d_in[7];
    const float* bn2b = (const float*)d_in[8];
    const float* c3w  = (const float*)d_in[9];
    const float* c3b  = (const float*)d_in[10];
    const float* bn3g = (const float*)d_in[11];
    const float* bn3b = (const float*)d_in[12];
    const float* d1w  = (const float*)d_in[13];
    const float* d1b  = (const float*)d_in[14];
    const float* bn4g = (const float*)d_in[15];
    const float* bn4b = (const float*)d_in[16];
    const float* d2w  = (const float*)d_in[17];
    const float* d2b  = (const float*)d_in[18];
    const float* d3w  = (const float*)d_in[19];
    const float* d3b  = (const float*)d_in[20];
    const int* types  = (const int*)d_in[22];   // d_in[21]=batch_ids implied by layout

    float* ws = (float*)d_ws;
    float* st = ws;                         // 480 f (bn stats; small arrays first)
    float* a3 = ws + 512;                   // 16,384 f
    float* h1 = a3 + 16384;                 // 32,768 f
    float* a2 = h1 + 32768;                 // 221,184 f
    float* a1 = a2 + 221184;                // 2,985,984 f   (total ~13 MB)

    hipMemsetAsync(st, 0, 480 * sizeof(float), stream);
    k_blur_conv1<<<BATCH, 512, 0, stream>>>(pos, types, c1w, c1b, a1, st);
    k_conv2     <<<BATCH, 512, 0, stream>>>(a1, c2w, c2b, bn1g, bn1b, st, a2, st + 32);
    k_conv3     <<<BATCH, 256, 0, stream>>>(a2, c3w, c3b, bn2g, bn2b, st + 32, a3, st + 96);
    k_dense1    <<<BATCH, 128, 0, stream>>>(a3, bn3g, bn3b, st + 96, d1w, d1b, h1, st + 224);
    k_dense2    <<<BATCH, 128, 0, stream>>>(h1, bn4g, bn4b, st + 224, d2w, d2b, d3w, d3b,
                                            (float*)d_out);
}